// Round 9
// baseline (274.829 us; speedup 1.0000x reference)
//
#include <hip/hip_runtime.h>
#include <hip/hip_bf16.h>
#include <math.h>

#define DIM 192
#define NB  16
#define NH  64
#define NW  64
#define NT  4096   // NH*NW

#define BN   48    // qkv block N-tile (cols of W per block)
#define NKG  24    // 192/8 k-granules

typedef __attribute__((ext_vector_type(8))) short short8;
typedef __attribute__((ext_vector_type(4))) float f32x4;
typedef __attribute__((address_space(3))) void* as3_void;
typedef const __attribute__((address_space(1))) void* as1_cvoid;

__device__ __forceinline__ unsigned short f2bf(float x) {
    unsigned int u = __float_as_uint(x);
    u = u + 0x7fffu + ((u >> 16) & 1u);
    return (unsigned short)(u >> 16);
}
__device__ __forceinline__ float bf2f(unsigned short h) {
    return __uint_as_float(((unsigned int)h) << 16);
}
__device__ __forceinline__ void gload16(const void* g, void* l) {
    __builtin_amdgcn_global_load_lds((as1_cvoid)g, (as3_void)l, 16, 0, 0);
}

// ---------------------------------------------------------------------------
// Kernel 1: prep (parallel). Block 0: fold the three depthwise kernels into
// one 5x5 per channel. Blocks 1..576: split packed [Wk;Wv;Wr;Wo] -> bf16 hi/lo.
__global__ void k_prep(const float* __restrict__ w1, const float* __restrict__ w3,
                       const float* __restrict__ w5, const float* __restrict__ alpha,
                       const float* __restrict__ Wk, const float* __restrict__ Wv,
                       const float* __restrict__ Wr, const float* __restrict__ Wo,
                       float* __restrict__ wc,
                       unsigned short* __restrict__ Whi,
                       unsigned short* __restrict__ Wlo) {
    int bid = blockIdx.x, tid = threadIdx.x;
    if (bid == 0) {
        if (tid < DIM) {
            int c = tid;
            float a0 = alpha[0], a1 = alpha[1], a2 = alpha[2], a3 = alpha[3];
            #pragma unroll
            for (int kh = 0; kh < 5; ++kh)
                #pragma unroll
                for (int kw = 0; kw < 5; ++kw) {
                    float v = a3 * w5[c * 25 + kh * 5 + kw];
                    if (kh >= 1 && kh <= 3 && kw >= 1 && kw <= 3)
                        v += a2 * w3[c * 9 + (kh - 1) * 3 + (kw - 1)];
                    if (kh == 2 && kw == 2)
                        v += a0 + a1 * w1[c];
                    wc[c * 25 + kh * 5 + kw] = v;
                }
        }
        return;
    }
    int e = (bid - 1) * 256 + tid;
    if (e >= 4 * DIM * DIM) return;
    int mat = e / (DIM * DIM);
    int idx = e - mat * DIM * DIM;
    const float* W = (mat == 0) ? Wk : (mat == 1 ? Wv : (mat == 2 ? Wr : Wo));
    float v = W[idx];
    unsigned short h = f2bf(v);
    Whi[e] = h;
    Wlo[e] = f2bf(v - bf2f(h));
}

// ---------------------------------------------------------------------------
// Kernel 2: depthwise 5x5 conv, sliding-column register window.
// Emits xs split into bf16 hi/lo, row-major [t][c] (c contiguous).
__global__ __launch_bounds__(192) void k_conv(const float* __restrict__ x,
                                              const float* __restrict__ wc,
                                              unsigned short* __restrict__ xs_hi,
                                              unsigned short* __restrict__ xs_lo) {
    int c  = threadIdx.x;
    int bh = blockIdx.x;
    int b = bh >> 6, h = bh & 63;
    const float* xb = x + (size_t)b * NT * DIM + c;
    size_t obase = ((size_t)b * NT + (size_t)h * NW) * DIM + c;

    float wgt[25];
    #pragma unroll
    for (int j = 0; j < 25; ++j) wgt[j] = wc[c * 25 + j];

    const float* rowp[5];
    bool rok[5];
    #pragma unroll
    for (int dh = 0; dh < 5; ++dh) {
        int hh = h + dh - 2;
        rok[dh] = (hh >= 0 && hh < NH);
        rowp[dh] = xb + (size_t)(rok[dh] ? hh : 0) * NW * DIM;
    }

    float win[5][5];
    #pragma unroll
    for (int dh = 0; dh < 5; ++dh) {
        win[dh][0] = 0.f; win[dh][1] = 0.f; win[dh][2] = 0.f;
        win[dh][3] = rok[dh] ? rowp[dh][(size_t)0 * DIM] : 0.f;
        win[dh][4] = rok[dh] ? rowp[dh][(size_t)1 * DIM] : 0.f;
    }

    for (int w = 0; w < NW; ++w) {
        int wcol = w + 2;
        bool cok = (wcol < NW);
        #pragma unroll
        for (int dh = 0; dh < 5; ++dh) {
            win[dh][0] = win[dh][1];
            win[dh][1] = win[dh][2];
            win[dh][2] = win[dh][3];
            win[dh][3] = win[dh][4];
            win[dh][4] = (rok[dh] && cok) ? rowp[dh][(size_t)wcol * DIM] : 0.f;
        }
        float acc = 0.f;
        #pragma unroll
        for (int dh = 0; dh < 5; ++dh)
            #pragma unroll
            for (int dw = 0; dw < 5; ++dw)
                acc = fmaf(win[dh][dw], wgt[dh * 5 + dw], acc);
        unsigned short hb = f2bf(acc);
        xs_hi[obase + (size_t)w * DIM] = hb;
        xs_lo[obase + (size_t)w * DIM] = f2bf(acc - bf2f(hb));
    }
}

// ---------------------------------------------------------------------------
// Kernel 3: k/v/r projections — W-stationary LDS + direct-global A fragments.
// Round-8 structure + (a) TWO m-tiles per block with a continuous pipeline
// across the boundary (W stays in LDS; m0's store overlaps m1's in-flight
// loads), halving per-block fill/drain + W-stage overhead; (b) 3 blocks/CU.

#define LOADA(AH, AL, ROW, KC)                                               \
    {                                                                        \
        _Pragma("unroll")                                                    \
        for (int mf = 0; mf < 4; ++mf) {                                     \
            size_t a = (size_t)((ROW) + mf * 16) * DIM + (KC) * 32 + kofs;   \
            AH[mf] = *(const short8*)&xs_hi[a];                              \
            AL[mf] = *(const short8*)&xs_lo[a];                              \
        }                                                                    \
    }

#define LOADB(BH, BL, KC)                                                    \
    {                                                                        \
        _Pragma("unroll")                                                    \
        for (int nf = 0; nf < 3; ++nf) {                                     \
            BH[nf] = *(const short8*)&Bs[0][(KC) * 4 + lkg][nf * 16 + l15][0]; \
            BL[nf] = *(const short8*)&Bs[1][(KC) * 4 + lkg][nf * 16 + l15][0]; \
        }                                                                    \
    }

#define COMP(AH, AL, BH, BL)                                                 \
    {                                                                        \
        _Pragma("unroll")                                                    \
        for (int mf = 0; mf < 4; ++mf)                                       \
            _Pragma("unroll")                                                \
            for (int nf = 0; nf < 3; ++nf)                                   \
                acc[mf][nf] = __builtin_amdgcn_mfma_f32_16x16x32_bf16(       \
                    AH[mf], BH[nf], acc[mf][nf], 0, 0, 0);                   \
        _Pragma("unroll")                                                    \
        for (int mf = 0; mf < 4; ++mf)                                       \
            _Pragma("unroll")                                                \
            for (int nf = 0; nf < 3; ++nf)                                   \
                acc[mf][nf] = __builtin_amdgcn_mfma_f32_16x16x32_bf16(       \
                    AH[mf], BL[nf], acc[mf][nf], 0, 0, 0);                   \
        _Pragma("unroll")                                                    \
        for (int mf = 0; mf < 4; ++mf)                                       \
            _Pragma("unroll")                                                \
            for (int nf = 0; nf < 3; ++nf)                                   \
                acc[mf][nf] = __builtin_amdgcn_mfma_f32_16x16x32_bf16(       \
                    AL[mf], BH[nf], acc[mf][nf], 0, 0, 0);                   \
    }

#define STOREACC(MB)                                                         \
    {                                                                        \
        const int b_  = (MB) >> 12;                                          \
        const int tb_ = ((MB) & 4095) + lkg * 4;                             \
        _Pragma("unroll")                                                    \
        for (int mf = 0; mf < 4; ++mf) {                                     \
            int t = tb_ + mf * 16;                                           \
            _Pragma("unroll")                                                \
            for (int nf = 0; nf < 3; ++nf) {                                 \
                int c = n0 + nf * 16 + l15;                                  \
                f32x4 v = acc[mf][nf];                                       \
                if (mat == 2) {                                              \
                    v.x = 1.0f / (1.0f + expf(-v.x));                        \
                    v.y = 1.0f / (1.0f + expf(-v.y));                        \
                    v.z = 1.0f / (1.0f + expf(-v.z));                        \
                    v.w = 1.0f / (1.0f + expf(-v.w));                        \
                }                                                            \
                *(f32x4*)&Out[((size_t)(b_ * DIM + c)) * NT + t] = v;        \
            }                                                                \
        }                                                                    \
    }

#define ZEROACC                                                              \
    {                                                                        \
        _Pragma("unroll")                                                    \
        for (int i = 0; i < 4; ++i)                                          \
            _Pragma("unroll")                                                \
            for (int j = 0; j < 3; ++j)                                      \
                acc[i][j] = (f32x4){0.f, 0.f, 0.f, 0.f};                     \
    }

#define FENCE __builtin_amdgcn_sched_barrier(0)

__global__ __launch_bounds__(256, 3) void k_gemm_qkv_ws(
        const unsigned short* __restrict__ xs_hi,
        const unsigned short* __restrict__ xs_lo,
        const unsigned short* __restrict__ Whi,
        const unsigned short* __restrict__ Wlo,
        float* __restrict__ kT, float* __restrict__ vT, float* __restrict__ srT) {
    __shared__ __align__(16) short Bs[2][NKG][BN][8];   // 36,864 B

    const int tid  = threadIdx.x;
    const int lane = tid & 63;
    const int wid  = tid >> 6;          // 0..3
    const int l15  = lane & 15;
    const int lkg  = lane >> 4;         // 0..3
    const int kofs = lkg * 8;

    // swizzle: 1536 blocks = 8 xcd * 16 mtile-pairs * 12 (slice,mat)
    const int bid   = blockIdx.x;
    const int xcd   = bid & 7;
    const int ix    = bid >> 3;         // 0..191
    const int pair  = ix / 12;          // 0..15
    const int sm    = ix % 12;
    const int slice = sm & 3;           // 0..3
    const int mat   = sm >> 2;          // 0..2
    const int n0    = slice * BN;

    const unsigned short* Wh = Whi + mat * (DIM * DIM);
    const unsigned short* Wl = Wlo + mat * (DIM * DIM);
    float* Out = (mat == 0) ? kT : (mat == 1 ? vT : srT);

    // ---- stage W slice (hi+lo) into LDS: 2304 granules, 9 rounds ----
    #pragma unroll
    for (int r = 0; r < 9; ++r) {
        int g  = r * 256 + tid;
        int g2 = (g >= 1152) ? g - 1152 : g;
        const unsigned short* src = (g >= 1152) ? Wl : Wh;
        int kg  = g2 / BN;
        int col = g2 - kg * BN;
        int doff = (r * 256 + wid * 64) * 16;   // wave-uniform base; HW adds lane*16
        gload16(src + (size_t)(n0 + col) * DIM + kg * 8, (char*)&Bs[0][0][0][0] + doff);
    }

    const int mbase0 = (xcd * 32 + pair * 2) * 256 + wid * 64;
    const int mbase1 = mbase0 + 256;
    const int arow0  = mbase0 + l15;
    const int arow1  = mbase1 + l15;

    f32x4 acc[4][3];
    ZEROACC

    short8 ah0[4], al0[4], ah1[4], al1[4];
    short8 bh0[3], bl0[3], bh1[3], bl1[3];

    LOADA(ah0, al0, arow0, 0)
    LOADA(ah1, al1, arow0, 1)
    __syncthreads();                      // W staged (barrier drains vmcnt)

    LOADB(bh0, bl0, 0)
    LOADB(bh1, bl1, 1)
    FENCE;
    COMP(ah0, al0, bh0, bl0)              // m0 k0
    FENCE;
    LOADA(ah0, al0, arow0, 2)
    LOADB(bh0, bl0, 2)
    FENCE;
    COMP(ah1, al1, bh1, bl1)              // m0 k1
    FENCE;
    LOADA(ah1, al1, arow0, 3)
    LOADB(bh1, bl1, 3)
    FENCE;
    COMP(ah0, al0, bh0, bl0)              // m0 k2
    FENCE;
    LOADA(ah0, al0, arow0, 4)
    LOADB(bh0, bl0, 4)
    FENCE;
    COMP(ah1, al1, bh1, bl1)              // m0 k3
    FENCE;
    LOADA(ah1, al1, arow0, 5)
    LOADB(bh1, bl1, 5)
    FENCE;
    COMP(ah0, al0, bh0, bl0)              // m0 k4
    FENCE;
    LOADA(ah0, al0, arow1, 0)             // prefetch m1 k0 across boundary
    LOADB(bh0, bl0, 0)
    FENCE;
    COMP(ah1, al1, bh1, bl1)              // m0 k5 -> m0 acc complete
    FENCE;
    STOREACC(mbase0)                      // overlaps m1's in-flight loads
    ZEROACC
    LOADA(ah1, al1, arow1, 1)
    LOADB(bh1, bl1, 1)
    FENCE;
    COMP(ah0, al0, bh0, bl0)              // m1 k0
    FENCE;
    LOADA(ah0, al0, arow1, 2)
    LOADB(bh0, bl0, 2)
    FENCE;
    COMP(ah1, al1, bh1, bl1)              // m1 k1
    FENCE;
    LOADA(ah1, al1, arow1, 3)
    LOADB(bh1, bl1, 3)
    FENCE;
    COMP(ah0, al0, bh0, bl0)              // m1 k2
    FENCE;
    LOADA(ah0, al0, arow1, 4)
    LOADB(bh0, bl0, 4)
    FENCE;
    COMP(ah1, al1, bh1, bl1)              // m1 k3
    FENCE;
    LOADA(ah1, al1, arow1, 5)
    LOADB(bh1, bl1, 5)
    FENCE;
    COMP(ah0, al0, bh0, bl0)              // m1 k4
    FENCE;
    COMP(ah1, al1, bh1, bl1)              // m1 k5
    STOREACC(mbase1)
}

// ---------------------------------------------------------------------------
// Kernel 4: bidirectional WKV4 (unchanged). One block per (b,c).
__global__ __launch_bounds__(256) void k_wkv(
        const float* __restrict__ kT, const float* __restrict__ vT,
        const float* __restrict__ srT, const float* __restrict__ decay,
        const float* __restrict__ boost, float* __restrict__ zT) {
    __shared__ float sa[256], sb[256];
    int bc = blockIdx.x;
    int c = bc % DIM;
    size_t base = (size_t)bc * NT;
    int tid = threadIdx.x;
    int t0 = tid * 16;

    float w  = decay[c] * (1.0f / 4096.0f);
    float u  = boost[c] * (1.0f / 4096.0f);
    float ew = expf(-w);
    float eu = expf(u);

    float ek[16], ekv[16], vv[16];
    #pragma unroll
    for (int j = 0; j < 16; j += 4) {
        float4 k4 = *(const float4*)&kT[base + t0 + j];
        float4 v4 = *(const float4*)&vT[base + t0 + j];
        ek[j + 0] = expf(k4.x); ek[j + 1] = expf(k4.y);
        ek[j + 2] = expf(k4.z); ek[j + 3] = expf(k4.w);
        vv[j + 0] = v4.x; vv[j + 1] = v4.y; vv[j + 2] = v4.z; vv[j + 3] = v4.w;
        ekv[j + 0] = ek[j + 0] * v4.x; ekv[j + 1] = ek[j + 1] * v4.y;
        ekv[j + 2] = ek[j + 2] * v4.z; ekv[j + 3] = ek[j + 3] * v4.w;
    }

    float r = ew * ew; r = r * r; r = r * r; r = r * r;   // ew^16

    float La = 0.f, Lb = 0.f;
    #pragma unroll
    for (int j = 0; j < 16; ++j) { La = fmaf(ew, La, ekv[j]); Lb = fmaf(ew, Lb, ek[j]); }
    sa[tid] = La; sb[tid] = Lb;
    __syncthreads();
    float f = r;
    for (int d = 1; d < 256; d <<= 1) {
        float ta = (tid >= d) ? sa[tid - d] : 0.f;
        float tb_ = (tid >= d) ? sb[tid - d] : 0.f;
        __syncthreads();
        sa[tid] = fmaf(f, ta, sa[tid]);
        sb[tid] = fmaf(f, tb_, sb[tid]);
        __syncthreads();
        f = f * f;
    }
    float Ca = (tid > 0) ? sa[tid - 1] : 0.f;
    float Cb = (tid > 0) ? sb[tid - 1] : 0.f;
    __syncthreads();

    float Ra = 0.f, Rb = 0.f;
    #pragma unroll
    for (int j = 15; j >= 0; --j) { Ra = fmaf(ew, Ra, ekv[j]); Rb = fmaf(ew, Rb, ek[j]); }
    sa[255 - tid] = Ra; sb[255 - tid] = Rb;
    __syncthreads();
    f = r;
    for (int d = 1; d < 256; d <<= 1) {
        float ta = (tid >= d) ? sa[tid - d] : 0.f;
        float tb_ = (tid >= d) ? sb[tid - d] : 0.f;
        __syncthreads();
        sa[tid] = fmaf(f, ta, sa[tid]);
        sb[tid] = fmaf(f, tb_, sb[tid]);
        __syncthreads();
        f = f * f;
    }
    float Da = (tid < 255) ? sa[254 - tid] : 0.f;
    float Db = (tid < 255) ? sb[254 - tid] : 0.f;

    float ab[16], bb[16];
    {
        float a = Da, bv = Db;
        #pragma unroll
        for (int j = 15; j >= 0; --j) {
            ab[j] = a; bb[j] = bv;
            a  = fmaf(ew, a, ekv[j]);
            bv = fmaf(ew, bv, ek[j]);
        }
    }
    float outv[16];
    {
        float a = Ca, bv = Cb;
        #pragma unroll
        for (int j = 0; j < 16; ++j) {
            float af = a, bf = bv;
            a  = fmaf(ew, a, ekv[j]);
            bv = fmaf(ew, bv, ek[j]);
            float euk = eu * ek[j];
            float num = af + ab[j] + euk * vv[j];
            float den = bf + bb[j] + euk;
            outv[j] = num / den;
        }
    }
    #pragma unroll
    for (int j = 0; j < 16; j += 4) {
        float4 s4 = *(const float4*)&srT[base + t0 + j];
        float4 o;
        o.x = s4.x * outv[j + 0];
        o.y = s4.y * outv[j + 1];
        o.z = s4.z * outv[j + 2];
        o.w = s4.w * outv[j + 3];
        *(float4*)&zT[base + t0 + j] = o;
    }
}

// ---------------------------------------------------------------------------
// Kernel 5: output projection via split-bf16 MFMA (unchanged from round 8).

#define OSTAGE(BF, KC)                                                       \
    {                                                                        \
        _Pragma("unroll")                                                    \
        for (int pass = 0; pass < 2; ++pass) {                               \
            int t = stq * 4 + pass * 64;                                     \
            const float* z0 = &zT[((size_t)(b * DIM + (KC) * 32 + cp * 2)) * NT + t0 + t]; \
            float4 v0 = *(const float4*)z0;                                  \
            float4 v1 = *(const float4*)(z0 + NT);                           \
            _Pragma("unroll")                                                \
            for (int j = 0; j < 4; ++j) {                                    \
                float f0 = ((const float*)&v0)[j];                           \
                float f1 = ((const float*)&v1)[j];                           \
                unsigned short h0 = f2bf(f0), h1 = f2bf(f1);                 \
                unsigned int hw = (unsigned int)h0 | ((unsigned int)h1 << 16); \
                unsigned int lw = (unsigned int)f2bf(f0 - bf2f(h0))          \
                                | ((unsigned int)f2bf(f1 - bf2f(h1)) << 16); \
                *(unsigned int*)&Ah[BF][t + j][cp * 2] = hw;                 \
                *(unsigned int*)&Al[BF][t + j][cp * 2] = lw;                 \
            }                                                                \
        }                                                                    \
    }

#define OCOMP(BF, KC)                                                        \
    {                                                                        \
        short8 afh[4], afl[4], bfh[3], bfl[3];                               \
        _Pragma("unroll")                                                    \
        for (int mf = 0; mf < 4; ++mf) {                                     \
            int row = wm * 64 + mf * 16 + l15;                               \
            afh[mf] = *(const short8*)&Ah[BF][row][lkg * 8];                 \
            afl[mf] = *(const short8*)&Al[BF][row][lkg * 8];                 \
        }                                                                    \
        _Pragma("unroll")                                                    \
        for (int nf = 0; nf < 3; ++nf) {                                     \
            size_t wb = (size_t)(n0 + wn * 48 + nf * 16 + l15) * DIM + (KC) * 32 + lkg * 8; \
            bfh[nf] = *(const short8*)&Wohi[wb];                             \
            bfl[nf] = *(const short8*)&Wolo[wb];                             \
        }                                                                    \
        _Pragma("unroll")                                                    \
        for (int mf = 0; mf < 4; ++mf)                                       \
            _Pragma("unroll")                                                \
            for (int nf = 0; nf < 3; ++nf)                                   \
                acc[mf][nf] = __builtin_amdgcn_mfma_f32_16x16x32_bf16(       \
                    afh[mf], bfh[nf], acc[mf][nf], 0, 0, 0);                 \
        _Pragma("unroll")                                                    \
        for (int mf = 0; mf < 4; ++mf)                                       \
            _Pragma("unroll")                                                \
            for (int nf = 0; nf < 3; ++nf)                                   \
                acc[mf][nf] = __builtin_amdgcn_mfma_f32_16x16x32_bf16(       \
                    afh[mf], bfl[nf], acc[mf][nf], 0, 0, 0);                 \
        _Pragma("unroll")                                                    \
        for (int mf = 0; mf < 4; ++mf)                                       \
            _Pragma("unroll")                                                \
            for (int nf = 0; nf < 3; ++nf)                                   \
                acc[mf][nf] = __builtin_amdgcn_mfma_f32_16x16x32_bf16(       \
                    afl[mf], bfh[nf], acc[mf][nf], 0, 0, 0);                 \
    }

__global__ __launch_bounds__(256) void k_gemm_out_mfma(
        const float* __restrict__ zT,
        const unsigned short* __restrict__ Wohi,
        const unsigned short* __restrict__ Wolo,
        float* __restrict__ out) {
    __shared__ __align__(16) unsigned short Ah[2][128][40];   // 80B rows
    __shared__ __align__(16) unsigned short Al[2][128][40];   // total 40,960B

    const int tid  = threadIdx.x;
    const int lane = tid & 63;
    const int wid  = tid >> 6;
    const int wm = wid >> 1, wn = wid & 1;
    const int l15 = lane & 15;
    const int lkg = lane >> 4;
    const int n0 = blockIdx.x * 96;
    const int m0 = (int)blockIdx.y * 128;
    const int b  = m0 >> 12;
    const int t0 = m0 & 4095;

    const int cp  = tid >> 4;       // 0..15 (c-pair within 32-c chunk)
    const int stq = tid & 15;       // 0..15 (t quad)

    f32x4 acc[4][3];
    #pragma unroll
    for (int i = 0; i < 4; ++i)
        #pragma unroll
        for (int j = 0; j < 3; ++j)
            acc[i][j] = (f32x4){0.f, 0.f, 0.f, 0.f};

    OSTAGE(0, 0)
    __syncthreads();
    #pragma unroll
    for (int kc = 0; kc < 6; ++kc) {
        if (kc < 5) OSTAGE((kc + 1) & 1, kc + 1)
        OCOMP(kc & 1, kc)
        __syncthreads();
    }

    #pragma unroll
    for (int mf = 0; mf < 4; ++mf) {
        int trow = m0 + wm * 64 + mf * 16 + lkg * 4;
        #pragma unroll
        for (int nf = 0; nf < 3; ++nf) {
            int ncol = n0 + wn * 48 + nf * 16 + l15;
            #pragma unroll
            for (int j = 0; j < 4; ++j)
                out[(size_t)(trow + j) * DIM + ncol] = acc[mf][nf][j];
        }
    }
}

// ---------------------------------------------------------------------------
extern "C" void kernel_launch(void* const* d_in, const int* in_sizes, int n_in,
                              void* d_out, int out_size, void* d_ws, size_t ws_size,
                              hipStream_t stream) {
    const float* x     = (const float*)d_in[0];
    const float* w1    = (const float*)d_in[1];
    const float* w3    = (const float*)d_in[2];
    const float* w5    = (const float*)d_in[3];
    const float* alpha = (const float*)d_in[4];
    const float* Wk    = (const float*)d_in[5];
    const float* Wv    = (const float*)d_in[6];
    const float* Wr    = (const float*)d_in[7];
    const float* Wo    = (const float*)d_in[8];
    const float* decay = (const float*)d_in[9];
    const float* boost = (const float*)d_in[10];
    float* out = (float*)d_out;
    float* ws  = (float*)d_ws;

    const size_t BIG = (size_t)NB * NT * DIM;   // 12,582,912 elements

    // layout (float offsets):
    float* wc = ws;                                          // [0, 4800)
    unsigned short* Whi = (unsigned short*)(ws + 8192);      // 4*36864 ushorts -> ends 81920
    unsigned short* Wlo = (unsigned short*)(ws + 81920);     // -> ends 155648
    unsigned short* xs_hi = (unsigned short*)(ws + 155648);  // BIG ushorts -> ends 6447104
    unsigned short* xs_lo = xs_hi + BIG;                     // -> ends 12738560
    float* kT  = ws + 12738560;                              // BIG floats
    float* vT  = kT + BIG;
    float* srT = vT + BIG;                                   // ends 50487296 floats
    float* zT  = ws + 155648;   // fp32, overlays xs_hi/xs_lo (dead after qkv)

    hipLaunchKernelGGL(k_prep, dim3(577), dim3(256), 0, stream,
                       w1, w3, w5, alpha, Wk, Wv, Wr, Wo, wc, Whi, Wlo);
    hipLaunchKernelGGL(k_conv, dim3(NB * NH), dim3(DIM), 0, stream,
                       x, wc, xs_hi, xs_lo);
    // 1536 blocks = 8 xcd * 16 mtile-pairs * 12 (slice,mat); swizzle in-kernel.
    hipLaunchKernelGGL(k_gemm_qkv_ws, dim3(1536), dim3(256), 0, stream,
                       xs_hi, xs_lo, Whi, Wlo, kT, vT, srT);
    hipLaunchKernelGGL(k_wkv, dim3(NB * DIM), dim3(256), 0, stream,
                       kT, vT, srT, decay, boost, zT);
    hipLaunchKernelGGL(k_gemm_out_mfma, dim3(2, 65536 / 128), dim3(256), 0, stream,
                       zT, Whi + 3 * DIM * DIM, Wlo + 3 * DIM * DIM, out);
}

// Round 10
// 241.036 us; speedup vs baseline: 1.1402x; 1.1402x over previous
//
#include <hip/hip_runtime.h>
#include <hip/hip_bf16.h>
#include <math.h>

#define DIM 192
#define NB  16
#define NH  64
#define NW  64
#define NT  4096   // NH*NW

#define BN   48    // qkv block N-tile (cols of W per block)
#define NKG  24    // 192/8 k-granules

typedef __attribute__((ext_vector_type(8))) short short8;
typedef __attribute__((ext_vector_type(4))) float f32x4;
typedef __attribute__((address_space(3))) void* as3_void;
typedef const __attribute__((address_space(1))) void* as1_cvoid;

__device__ __forceinline__ unsigned short f2bf(float x) {
    unsigned int u = __float_as_uint(x);
    u = u + 0x7fffu + ((u >> 16) & 1u);
    return (unsigned short)(u >> 16);
}
__device__ __forceinline__ float bf2f(unsigned short h) {
    return __uint_as_float(((unsigned int)h) << 16);
}
__device__ __forceinline__ void gload16(const void* g, void* l) {
    __builtin_amdgcn_global_load_lds((as1_cvoid)g, (as3_void)l, 16, 0, 0);
}

// ---------------------------------------------------------------------------
// Kernel 1: prep (parallel). Block 0: fold the three depthwise kernels into
// one 5x5 per channel. Blocks 1..576: split packed [Wk;Wv;Wr;Wo] -> bf16 hi/lo.
__global__ void k_prep(const float* __restrict__ w1, const float* __restrict__ w3,
                       const float* __restrict__ w5, const float* __restrict__ alpha,
                       const float* __restrict__ Wk, const float* __restrict__ Wv,
                       const float* __restrict__ Wr, const float* __restrict__ Wo,
                       float* __restrict__ wc,
                       unsigned short* __restrict__ Whi,
                       unsigned short* __restrict__ Wlo) {
    int bid = blockIdx.x, tid = threadIdx.x;
    if (bid == 0) {
        if (tid < DIM) {
            int c = tid;
            float a0 = alpha[0], a1 = alpha[1], a2 = alpha[2], a3 = alpha[3];
            #pragma unroll
            for (int kh = 0; kh < 5; ++kh)
                #pragma unroll
                for (int kw = 0; kw < 5; ++kw) {
                    float v = a3 * w5[c * 25 + kh * 5 + kw];
                    if (kh >= 1 && kh <= 3 && kw >= 1 && kw <= 3)
                        v += a2 * w3[c * 9 + (kh - 1) * 3 + (kw - 1)];
                    if (kh == 2 && kw == 2)
                        v += a0 + a1 * w1[c];
                    wc[c * 25 + kh * 5 + kw] = v;
                }
        }
        return;
    }
    int e = (bid - 1) * 256 + tid;
    if (e >= 4 * DIM * DIM) return;
    int mat = e / (DIM * DIM);
    int idx = e - mat * DIM * DIM;
    const float* W = (mat == 0) ? Wk : (mat == 1 ? Wv : (mat == 2 ? Wr : Wo));
    float v = W[idx];
    unsigned short h = f2bf(v);
    Whi[e] = h;
    Wlo[e] = f2bf(v - bf2f(h));
}

// ---------------------------------------------------------------------------
// Kernel 2: depthwise 5x5 conv, sliding-column register window.
// Emits xs split into bf16 hi/lo, row-major [t][c] (c contiguous).
__global__ __launch_bounds__(192) void k_conv(const float* __restrict__ x,
                                              const float* __restrict__ wc,
                                              unsigned short* __restrict__ xs_hi,
                                              unsigned short* __restrict__ xs_lo) {
    int c  = threadIdx.x;
    int bh = blockIdx.x;
    int b = bh >> 6, h = bh & 63;
    const float* xb = x + (size_t)b * NT * DIM + c;
    size_t obase = ((size_t)b * NT + (size_t)h * NW) * DIM + c;

    float wgt[25];
    #pragma unroll
    for (int j = 0; j < 25; ++j) wgt[j] = wc[c * 25 + j];

    const float* rowp[5];
    bool rok[5];
    #pragma unroll
    for (int dh = 0; dh < 5; ++dh) {
        int hh = h + dh - 2;
        rok[dh] = (hh >= 0 && hh < NH);
        rowp[dh] = xb + (size_t)(rok[dh] ? hh : 0) * NW * DIM;
    }

    float win[5][5];
    #pragma unroll
    for (int dh = 0; dh < 5; ++dh) {
        win[dh][0] = 0.f; win[dh][1] = 0.f; win[dh][2] = 0.f;
        win[dh][3] = rok[dh] ? rowp[dh][(size_t)0 * DIM] : 0.f;
        win[dh][4] = rok[dh] ? rowp[dh][(size_t)1 * DIM] : 0.f;
    }

    for (int w = 0; w < NW; ++w) {
        int wcol = w + 2;
        bool cok = (wcol < NW);
        #pragma unroll
        for (int dh = 0; dh < 5; ++dh) {
            win[dh][0] = win[dh][1];
            win[dh][1] = win[dh][2];
            win[dh][2] = win[dh][3];
            win[dh][3] = win[dh][4];
            win[dh][4] = (rok[dh] && cok) ? rowp[dh][(size_t)wcol * DIM] : 0.f;
        }
        float acc = 0.f;
        #pragma unroll
        for (int dh = 0; dh < 5; ++dh)
            #pragma unroll
            for (int dw = 0; dw < 5; ++dw)
                acc = fmaf(win[dh][dw], wgt[dh * 5 + dw], acc);
        unsigned short hb = f2bf(acc);
        xs_hi[obase + (size_t)w * DIM] = hb;
        xs_lo[obase + (size_t)w * DIM] = f2bf(acc - bf2f(hb));
    }
}

// ---------------------------------------------------------------------------
// Kernel 3: k/v/r projections — W-stationary LDS + direct-global A fragments.
// Round-8 shell (single m-tile, 3072 blocks, XCD swizzle, (256,2)); the one
// change: A pipeline depth 2 -> 3 (load->use distance = 2 COMPs ~ 350cy,
// covering L2/L3 latency). B stays 2-deep (LDS latency already covered).

#define LOADA(AH, AL, KC)                                                    \
    {                                                                        \
        _Pragma("unroll")                                                    \
        for (int mf = 0; mf < 4; ++mf) {                                     \
            size_t a = (size_t)(arow + mf * 16) * DIM + (KC) * 32 + kofs;    \
            AH[mf] = *(const short8*)&xs_hi[a];                              \
            AL[mf] = *(const short8*)&xs_lo[a];                              \
        }                                                                    \
    }

#define LOADB(BH, BL, KC)                                                    \
    {                                                                        \
        _Pragma("unroll")                                                    \
        for (int nf = 0; nf < 3; ++nf) {                                     \
            BH[nf] = *(const short8*)&Bs[0][(KC) * 4 + lkg][nf * 16 + l15][0]; \
            BL[nf] = *(const short8*)&Bs[1][(KC) * 4 + lkg][nf * 16 + l15][0]; \
        }                                                                    \
    }

#define COMP(AH, AL, BH, BL)                                                 \
    {                                                                        \
        _Pragma("unroll")                                                    \
        for (int mf = 0; mf < 4; ++mf)                                       \
            _Pragma("unroll")                                                \
            for (int nf = 0; nf < 3; ++nf)                                   \
                acc[mf][nf] = __builtin_amdgcn_mfma_f32_16x16x32_bf16(       \
                    AH[mf], BH[nf], acc[mf][nf], 0, 0, 0);                   \
        _Pragma("unroll")                                                    \
        for (int mf = 0; mf < 4; ++mf)                                       \
            _Pragma("unroll")                                                \
            for (int nf = 0; nf < 3; ++nf)                                   \
                acc[mf][nf] = __builtin_amdgcn_mfma_f32_16x16x32_bf16(       \
                    AH[mf], BL[nf], acc[mf][nf], 0, 0, 0);                   \
        _Pragma("unroll")                                                    \
        for (int mf = 0; mf < 4; ++mf)                                       \
            _Pragma("unroll")                                                \
            for (int nf = 0; nf < 3; ++nf)                                   \
                acc[mf][nf] = __builtin_amdgcn_mfma_f32_16x16x32_bf16(       \
                    AL[mf], BH[nf], acc[mf][nf], 0, 0, 0);                   \
    }

#define FENCE __builtin_amdgcn_sched_barrier(0)

__global__ __launch_bounds__(256, 2) void k_gemm_qkv_ws(
        const unsigned short* __restrict__ xs_hi,
        const unsigned short* __restrict__ xs_lo,
        const unsigned short* __restrict__ Whi,
        const unsigned short* __restrict__ Wlo,
        float* __restrict__ kT, float* __restrict__ vT, float* __restrict__ srT) {
    __shared__ __align__(16) short Bs[2][NKG][BN][8];   // 36,864 B

    const int tid  = threadIdx.x;
    const int lane = tid & 63;
    const int wid  = tid >> 6;          // 0..3
    const int l15  = lane & 15;
    const int lkg  = lane >> 4;         // 0..3
    const int kofs = lkg * 8;

    // XCD-aware swizzle: 3072 blocks = 8 xcd * 32 mtiles * 12 (slice,mat)
    const int bid   = blockIdx.x;
    const int xcd   = bid & 7;
    const int ix    = bid >> 3;         // 0..383
    const int mtile = xcd * 32 + ix / 12;
    const int sm    = ix % 12;
    const int slice = sm & 3;           // 0..3
    const int mat   = sm >> 2;          // 0..2
    const int n0    = slice * BN;

    const unsigned short* Wh = Whi + mat * (DIM * DIM);
    const unsigned short* Wl = Wlo + mat * (DIM * DIM);
    float* Out = (mat == 0) ? kT : (mat == 1 ? vT : srT);

    // ---- stage W slice (hi+lo) into LDS: 2304 granules, 9 rounds ----
    #pragma unroll
    for (int r = 0; r < 9; ++r) {
        int g  = r * 256 + tid;
        int g2 = (g >= 1152) ? g - 1152 : g;
        const unsigned short* src = (g >= 1152) ? Wl : Wh;
        int kg  = g2 / BN;
        int col = g2 - kg * BN;
        int doff = (r * 256 + wid * 64) * 16;   // wave-uniform base; HW adds lane*16
        gload16(src + (size_t)(n0 + col) * DIM + kg * 8, (char*)&Bs[0][0][0][0] + doff);
    }

    const int mbase = mtile * 256 + wid * 64;   // wave's 64 rows
    const int arow  = mbase + l15;

    f32x4 acc[4][3];
    #pragma unroll
    for (int i = 0; i < 4; ++i)
        #pragma unroll
        for (int j = 0; j < 3; ++j)
            acc[i][j] = (f32x4){0.f, 0.f, 0.f, 0.f};

    short8 ah0[4], al0[4], ah1[4], al1[4], ah2[4], al2[4];
    short8 bh0[3], bl0[3], bh1[3], bl1[3];

    // 3-deep A prefetch (global, VGPR); barrier drains with W staging
    LOADA(ah0, al0, 0)
    LOADA(ah1, al1, 1)
    LOADA(ah2, al2, 2)
    __syncthreads();                      // W staged

    LOADB(bh0, bl0, 0)
    LOADB(bh1, bl1, 1)
    FENCE;
    COMP(ah0, al0, bh0, bl0)              // k0
    FENCE;
    LOADA(ah0, al0, 3)
    LOADB(bh0, bl0, 2)
    FENCE;
    COMP(ah1, al1, bh1, bl1)              // k1
    FENCE;
    LOADA(ah1, al1, 4)
    LOADB(bh1, bl1, 3)
    FENCE;
    COMP(ah2, al2, bh0, bl0)              // k2
    FENCE;
    LOADA(ah2, al2, 5)
    LOADB(bh0, bl0, 4)
    FENCE;
    COMP(ah0, al0, bh1, bl1)              // k3
    FENCE;
    LOADB(bh1, bl1, 5)
    FENCE;
    COMP(ah1, al1, bh0, bl0)              // k4
    FENCE;
    COMP(ah2, al2, bh1, bl1)              // k5

    const int b  = mbase >> 12;
    const int tb = (mbase & 4095) + lkg * 4;
    #pragma unroll
    for (int mf = 0; mf < 4; ++mf) {
        int t = tb + mf * 16;
        #pragma unroll
        for (int nf = 0; nf < 3; ++nf) {
            int c = n0 + nf * 16 + l15;
            f32x4 v = acc[mf][nf];
            if (mat == 2) {
                v.x = 1.0f / (1.0f + expf(-v.x));
                v.y = 1.0f / (1.0f + expf(-v.y));
                v.z = 1.0f / (1.0f + expf(-v.z));
                v.w = 1.0f / (1.0f + expf(-v.w));
            }
            *(f32x4*)&Out[((size_t)(b * DIM + c)) * NT + t] = v;
        }
    }
}

// ---------------------------------------------------------------------------
// Kernel 4: bidirectional WKV4 (unchanged). One block per (b,c).
__global__ __launch_bounds__(256) void k_wkv(
        const float* __restrict__ kT, const float* __restrict__ vT,
        const float* __restrict__ srT, const float* __restrict__ decay,
        const float* __restrict__ boost, float* __restrict__ zT) {
    __shared__ float sa[256], sb[256];
    int bc = blockIdx.x;
    int c = bc % DIM;
    size_t base = (size_t)bc * NT;
    int tid = threadIdx.x;
    int t0 = tid * 16;

    float w  = decay[c] * (1.0f / 4096.0f);
    float u  = boost[c] * (1.0f / 4096.0f);
    float ew = expf(-w);
    float eu = expf(u);

    float ek[16], ekv[16], vv[16];
    #pragma unroll
    for (int j = 0; j < 16; j += 4) {
        float4 k4 = *(const float4*)&kT[base + t0 + j];
        float4 v4 = *(const float4*)&vT[base + t0 + j];
        ek[j + 0] = expf(k4.x); ek[j + 1] = expf(k4.y);
        ek[j + 2] = expf(k4.z); ek[j + 3] = expf(k4.w);
        vv[j + 0] = v4.x; vv[j + 1] = v4.y; vv[j + 2] = v4.z; vv[j + 3] = v4.w;
        ekv[j + 0] = ek[j + 0] * v4.x; ekv[j + 1] = ek[j + 1] * v4.y;
        ekv[j + 2] = ek[j + 2] * v4.z; ekv[j + 3] = ek[j + 3] * v4.w;
    }

    float r = ew * ew; r = r * r; r = r * r; r = r * r;   // ew^16

    float La = 0.f, Lb = 0.f;
    #pragma unroll
    for (int j = 0; j < 16; ++j) { La = fmaf(ew, La, ekv[j]); Lb = fmaf(ew, Lb, ek[j]); }
    sa[tid] = La; sb[tid] = Lb;
    __syncthreads();
    float f = r;
    for (int d = 1; d < 256; d <<= 1) {
        float ta = (tid >= d) ? sa[tid - d] : 0.f;
        float tb_ = (tid >= d) ? sb[tid - d] : 0.f;
        __syncthreads();
        sa[tid] = fmaf(f, ta, sa[tid]);
        sb[tid] = fmaf(f, tb_, sb[tid]);
        __syncthreads();
        f = f * f;
    }
    float Ca = (tid > 0) ? sa[tid - 1] : 0.f;
    float Cb = (tid > 0) ? sb[tid - 1] : 0.f;
    __syncthreads();

    float Ra = 0.f, Rb = 0.f;
    #pragma unroll
    for (int j = 15; j >= 0; --j) { Ra = fmaf(ew, Ra, ekv[j]); Rb = fmaf(ew, Rb, ek[j]); }
    sa[255 - tid] = Ra; sb[255 - tid] = Rb;
    __syncthreads();
    f = r;
    for (int d = 1; d < 256; d <<= 1) {
        float ta = (tid >= d) ? sa[tid - d] : 0.f;
        float tb_ = (tid >= d) ? sb[tid - d] : 0.f;
        __syncthreads();
        sa[tid] = fmaf(f, ta, sa[tid]);
        sb[tid] = fmaf(f, tb_, sb[tid]);
        __syncthreads();
        f = f * f;
    }
    float Da = (tid < 255) ? sa[254 - tid] : 0.f;
    float Db = (tid < 255) ? sb[254 - tid] : 0.f;

    float ab[16], bb[16];
    {
        float a = Da, bv = Db;
        #pragma unroll
        for (int j = 15; j >= 0; --j) {
            ab[j] = a; bb[j] = bv;
            a  = fmaf(ew, a, ekv[j]);
            bv = fmaf(ew, bv, ek[j]);
        }
    }
    float outv[16];
    {
        float a = Ca, bv = Cb;
        #pragma unroll
        for (int j = 0; j < 16; ++j) {
            float af = a, bf = bv;
            a  = fmaf(ew, a, ekv[j]);
            bv = fmaf(ew, bv, ek[j]);
            float euk = eu * ek[j];
            float num = af + ab[j] + euk * vv[j];
            float den = bf + bb[j] + euk;
            outv[j] = num / den;
        }
    }
    #pragma unroll
    for (int j = 0; j < 16; j += 4) {
        float4 s4 = *(const float4*)&srT[base + t0 + j];
        float4 o;
        o.x = s4.x * outv[j + 0];
        o.y = s4.y * outv[j + 1];
        o.z = s4.z * outv[j + 2];
        o.w = s4.w * outv[j + 3];
        *(float4*)&zT[base + t0 + j] = o;
    }
}

// ---------------------------------------------------------------------------
// Kernel 5: output projection via split-bf16 MFMA (unchanged from round 8).

#define OSTAGE(BF, KC)                                                       \
    {                                                                        \
        _Pragma("unroll")                                                    \
        for (int pass = 0; pass < 2; ++pass) {                               \
            int t = stq * 4 + pass * 64;                                     \
            const float* z0 = &zT[((size_t)(b * DIM + (KC) * 32 + cp * 2)) * NT + t0 + t]; \
            float4 v0 = *(const float4*)z0;                                  \
            float4 v1 = *(const float4*)(z0 + NT);                           \
            _Pragma("unroll")                                                \
            for (int j = 0; j < 4; ++j) {                                    \
                float f0 = ((const float*)&v0)[j];                           \
                float f1 = ((const float*)&v1)[j];                           \
                unsigned short h0 = f2bf(f0), h1 = f2bf(f1);                 \
                unsigned int hw = (unsigned int)h0 | ((unsigned int)h1 << 16); \
                unsigned int lw = (unsigned int)f2bf(f0 - bf2f(h0))          \
                                | ((unsigned int)f2bf(f1 - bf2f(h1)) << 16); \
                *(unsigned int*)&Ah[BF][t + j][cp * 2] = hw;                 \
                *(unsigned int*)&Al[BF][t + j][cp * 2] = lw;                 \
            }                                                                \
        }                                                                    \
    }

#define OCOMP(BF, KC)                                                        \
    {                                                                        \
        short8 afh[4], afl[4], bfh[3], bfl[3];                               \
        _Pragma("unroll")                                                    \
        for (int mf = 0; mf < 4; ++mf) {                                     \
            int row = wm * 64 + mf * 16 + l15;                               \
            afh[mf] = *(const short8*)&Ah[BF][row][lkg * 8];                 \
            afl[mf] = *(const short8*)&Al[BF][row][lkg * 8];                 \
        }                                                                    \
        _Pragma("unroll")                                                    \
        for (int nf = 0; nf < 3; ++nf) {                                     \
            size_t wb = (size_t)(n0 + wn * 48 + nf * 16 + l15) * DIM + (KC) * 32 + lkg * 8; \
            bfh[nf] = *(const short8*)&Wohi[wb];                             \
            bfl[nf] = *(const short8*)&Wolo[wb];                             \
        }                                                                    \
        _Pragma("unroll")                                                    \
        for (int mf = 0; mf < 4; ++mf)                                       \
            _Pragma("unroll")                                                \
            for (int nf = 0; nf < 3; ++nf)                                   \
                acc[mf][nf] = __builtin_amdgcn_mfma_f32_16x16x32_bf16(       \
                    afh[mf], bfh[nf], acc[mf][nf], 0, 0, 0);                 \
        _Pragma("unroll")                                                    \
        for (int mf = 0; mf < 4; ++mf)                                       \
            _Pragma("unroll")                                                \
            for (int nf = 0; nf < 3; ++nf)                                   \
                acc[mf][nf] = __builtin_amdgcn_mfma_f32_16x16x32_bf16(       \
                    afh[mf], bfl[nf], acc[mf][nf], 0, 0, 0);                 \
        _Pragma("unroll")                                                    \
        for (int mf = 0; mf < 4; ++mf)                                       \
            _Pragma("unroll")                                                \
            for (int nf = 0; nf < 3; ++nf)                                   \
                acc[mf][nf] = __builtin_amdgcn_mfma_f32_16x16x32_bf16(       \
                    afl[mf], bfh[nf], acc[mf][nf], 0, 0, 0);                 \
    }

__global__ __launch_bounds__(256) void k_gemm_out_mfma(
        const float* __restrict__ zT,
        const unsigned short* __restrict__ Wohi,
        const unsigned short* __restrict__ Wolo,
        float* __restrict__ out) {
    __shared__ __align__(16) unsigned short Ah[2][128][40];   // 80B rows
    __shared__ __align__(16) unsigned short Al[2][128][40];   // total 40,960B

    const int tid  = threadIdx.x;
    const int lane = tid & 63;
    const int wid  = tid >> 6;
    const int wm = wid >> 1, wn = wid & 1;
    const int l15 = lane & 15;
    const int lkg = lane >> 4;
    const int n0 = blockIdx.x * 96;
    const int m0 = (int)blockIdx.y * 128;
    const int b  = m0 >> 12;
    const int t0 = m0 & 4095;

    const int cp  = tid >> 4;       // 0..15 (c-pair within 32-c chunk)
    const int stq = tid & 15;       // 0..15 (t quad)

    f32x4 acc[4][3];
    #pragma unroll
    for (int i = 0; i < 4; ++i)
        #pragma unroll
        for (int j = 0; j < 3; ++j)
            acc[i][j] = (f32x4){0.f, 0.f, 0.f, 0.f};

    OSTAGE(0, 0)
    __syncthreads();
    #pragma unroll
    for (int kc = 0; kc < 6; ++kc) {
        if (kc < 5) OSTAGE((kc + 1) & 1, kc + 1)
        OCOMP(kc & 1, kc)
        __syncthreads();
    }

    #pragma unroll
    for (int mf = 0; mf < 4; ++mf) {
        int trow = m0 + wm * 64 + mf * 16 + lkg * 4;
        #pragma unroll
        for (int nf = 0; nf < 3; ++nf) {
            int ncol = n0 + wn * 48 + nf * 16 + l15;
            #pragma unroll
            for (int j = 0; j < 4; ++j)
                out[(size_t)(trow + j) * DIM + ncol] = acc[mf][nf][j];
        }
    }
}

// ---------------------------------------------------------------------------
extern "C" void kernel_launch(void* const* d_in, const int* in_sizes, int n_in,
                              void* d_out, int out_size, void* d_ws, size_t ws_size,
                              hipStream_t stream) {
    const float* x     = (const float*)d_in[0];
    const float* w1    = (const float*)d_in[1];
    const float* w3    = (const float*)d_in[2];
    const float* w5    = (const float*)d_in[3];
    const float* alpha = (const float*)d_in[4];
    const float* Wk    = (const float*)d_in[5];
    const float* Wv    = (const float*)d_in[6];
    const float* Wr    = (const float*)d_in[7];
    const float* Wo    = (const float*)d_in[8];
    const float* decay = (const float*)d_in[9];
    const float* boost = (const float*)d_in[10];
    float* out = (float*)d_out;
    float* ws  = (float*)d_ws;

    const size_t BIG = (size_t)NB * NT * DIM;   // 12,582,912 elements

    // layout (float offsets):
    float* wc = ws;                                          // [0, 4800)
    unsigned short* Whi = (unsigned short*)(ws + 8192);      // 4*36864 ushorts -> ends 81920
    unsigned short* Wlo = (unsigned short*)(ws + 81920);     // -> ends 155648
    unsigned short* xs_hi = (unsigned short*)(ws + 155648);  // BIG ushorts -> ends 6447104
    unsigned short* xs_lo = xs_hi + BIG;                     // -> ends 12738560
    float* kT  = ws + 12738560;                              // BIG floats
    float* vT  = kT + BIG;
    float* srT = vT + BIG;                                   // ends 50487296 floats
    float* zT  = ws + 155648;   // fp32, overlays xs_hi/xs_lo (dead after qkv)

    hipLaunchKernelGGL(k_prep, dim3(577), dim3(256), 0, stream,
                       w1, w3, w5, alpha, Wk, Wv, Wr, Wo, wc, Whi, Wlo);
    hipLaunchKernelGGL(k_conv, dim3(NB * NH), dim3(DIM), 0, stream,
                       x, wc, xs_hi, xs_lo);
    // 3072 blocks = 8 xcd * 32 mtiles * 12 (slice,mat); swizzle in-kernel.
    hipLaunchKernelGGL(k_gemm_qkv_ws, dim3(3072), dim3(256), 0, stream,
                       xs_hi, xs_lo, Whi, Wlo, kT, vT, srT);
    hipLaunchKernelGGL(k_wkv, dim3(NB * DIM), dim3(256), 0, stream,
                       kT, vT, srT, decay, boost, zT);
    hipLaunchKernelGGL(k_gemm_out_mfma, dim3(2, 65536 / 128), dim3(256), 0, stream,
                       zT, Whi + 3 * DIM * DIM, Wlo + 3 * DIM * DIM, out);
}

// Round 11
// 240.613 us; speedup vs baseline: 1.1422x; 1.0018x over previous
//
#include <hip/hip_runtime.h>
#include <hip/hip_bf16.h>
#include <math.h>

#define DIM 192
#define NB  16
#define NH  64
#define NW  64
#define NT  4096   // NH*NW

#define BN   48    // qkv block N-tile (cols of W per block)
#define NKG  24    // 192/8 k-granules

typedef __attribute__((ext_vector_type(8))) short short8;
typedef __attribute__((ext_vector_type(4))) float f32x4;
typedef __attribute__((address_space(3))) void* as3_void;
typedef const __attribute__((address_space(1))) void* as1_cvoid;

__device__ __forceinline__ unsigned short f2bf(float x) {
    unsigned int u = __float_as_uint(x);
    u = u + 0x7fffu + ((u >> 16) & 1u);
    return (unsigned short)(u >> 16);
}
__device__ __forceinline__ float bf2f(unsigned short h) {
    return __uint_as_float(((unsigned int)h) << 16);
}
__device__ __forceinline__ void gload16(const void* g, void* l) {
    __builtin_amdgcn_global_load_lds((as1_cvoid)g, (as3_void)l, 16, 0, 0);
}

// ---------------------------------------------------------------------------
// Kernel 1: prep (parallel). Block 0: fold the three depthwise kernels into
// one 5x5 per channel. Blocks 1..576: split packed [Wk;Wv;Wr;Wo] -> bf16 hi/lo.
__global__ void k_prep(const float* __restrict__ w1, const float* __restrict__ w3,
                       const float* __restrict__ w5, const float* __restrict__ alpha,
                       const float* __restrict__ Wk, const float* __restrict__ Wv,
                       const float* __restrict__ Wr, const float* __restrict__ Wo,
                       float* __restrict__ wc,
                       unsigned short* __restrict__ Whi,
                       unsigned short* __restrict__ Wlo) {
    int bid = blockIdx.x, tid = threadIdx.x;
    if (bid == 0) {
        if (tid < DIM) {
            int c = tid;
            float a0 = alpha[0], a1 = alpha[1], a2 = alpha[2], a3 = alpha[3];
            #pragma unroll
            for (int kh = 0; kh < 5; ++kh)
                #pragma unroll
                for (int kw = 0; kw < 5; ++kw) {
                    float v = a3 * w5[c * 25 + kh * 5 + kw];
                    if (kh >= 1 && kh <= 3 && kw >= 1 && kw <= 3)
                        v += a2 * w3[c * 9 + (kh - 1) * 3 + (kw - 1)];
                    if (kh == 2 && kw == 2)
                        v += a0 + a1 * w1[c];
                    wc[c * 25 + kh * 5 + kw] = v;
                }
        }
        return;
    }
    int e = (bid - 1) * 256 + tid;
    if (e >= 4 * DIM * DIM) return;
    int mat = e / (DIM * DIM);
    int idx = e - mat * DIM * DIM;
    const float* W = (mat == 0) ? Wk : (mat == 1 ? Wv : (mat == 2 ? Wr : Wo));
    float v = W[idx];
    unsigned short h = f2bf(v);
    Whi[e] = h;
    Wlo[e] = f2bf(v - bf2f(h));
}

// ---------------------------------------------------------------------------
// Kernel 2: depthwise 5x5 conv, sliding-column register window.
// Emits xs split into bf16 hi/lo, row-major [t][c] (c contiguous).
__global__ __launch_bounds__(192) void k_conv(const float* __restrict__ x,
                                              const float* __restrict__ wc,
                                              unsigned short* __restrict__ xs_hi,
                                              unsigned short* __restrict__ xs_lo) {
    int c  = threadIdx.x;
    int bh = blockIdx.x;
    int b = bh >> 6, h = bh & 63;
    const float* xb = x + (size_t)b * NT * DIM + c;
    size_t obase = ((size_t)b * NT + (size_t)h * NW) * DIM + c;

    float wgt[25];
    #pragma unroll
    for (int j = 0; j < 25; ++j) wgt[j] = wc[c * 25 + j];

    const float* rowp[5];
    bool rok[5];
    #pragma unroll
    for (int dh = 0; dh < 5; ++dh) {
        int hh = h + dh - 2;
        rok[dh] = (hh >= 0 && hh < NH);
        rowp[dh] = xb + (size_t)(rok[dh] ? hh : 0) * NW * DIM;
    }

    float win[5][5];
    #pragma unroll
    for (int dh = 0; dh < 5; ++dh) {
        win[dh][0] = 0.f; win[dh][1] = 0.f; win[dh][2] = 0.f;
        win[dh][3] = rok[dh] ? rowp[dh][(size_t)0 * DIM] : 0.f;
        win[dh][4] = rok[dh] ? rowp[dh][(size_t)1 * DIM] : 0.f;
    }

    for (int w = 0; w < NW; ++w) {
        int wcol = w + 2;
        bool cok = (wcol < NW);
        #pragma unroll
        for (int dh = 0; dh < 5; ++dh) {
            win[dh][0] = win[dh][1];
            win[dh][1] = win[dh][2];
            win[dh][2] = win[dh][3];
            win[dh][3] = win[dh][4];
            win[dh][4] = (rok[dh] && cok) ? rowp[dh][(size_t)wcol * DIM] : 0.f;
        }
        float acc = 0.f;
        #pragma unroll
        for (int dh = 0; dh < 5; ++dh)
            #pragma unroll
            for (int dw = 0; dw < 5; ++dw)
                acc = fmaf(win[dh][dw], wgt[dh * 5 + dw], acc);
        unsigned short hb = f2bf(acc);
        xs_hi[obase + (size_t)w * DIM] = hb;
        xs_lo[obase + (size_t)w * DIM] = f2bf(acc - bf2f(hb));
    }
}

// ---------------------------------------------------------------------------
// Kernel 3: k/v/r projections — W-stationary LDS + direct-global A fragments.
// Round-10 shell; the one change: each block now processes FOUR m-tiles in a
// rolling loop (register rotation mod-aligned: 6 chunks ≡ 0 mod 3 A-sets /
// 2 B-sets), amortizing W-stage + barrier + fill/drain + epilogue 4x.
// Grid 768 = 8 xcd * 8 groups * 12 (slice,mat).

#define LOADA(AH, AL, ROW, KC)                                               \
    {                                                                        \
        _Pragma("unroll")                                                    \
        for (int mf = 0; mf < 4; ++mf) {                                     \
            size_t a = (size_t)((ROW) + mf * 16) * DIM + (KC) * 32 + kofs;   \
            AH[mf] = *(const short8*)&xs_hi[a];                              \
            AL[mf] = *(const short8*)&xs_lo[a];                              \
        }                                                                    \
    }

#define LOADB(BH, BL, KC)                                                    \
    {                                                                        \
        _Pragma("unroll")                                                    \
        for (int nf = 0; nf < 3; ++nf) {                                     \
            BH[nf] = *(const short8*)&Bs[0][(KC) * 4 + lkg][nf * 16 + l15][0]; \
            BL[nf] = *(const short8*)&Bs[1][(KC) * 4 + lkg][nf * 16 + l15][0]; \
        }                                                                    \
    }

#define COMP(AH, AL, BH, BL)                                                 \
    {                                                                        \
        _Pragma("unroll")                                                    \
        for (int mf = 0; mf < 4; ++mf)                                       \
            _Pragma("unroll")                                                \
            for (int nf = 0; nf < 3; ++nf)                                   \
                acc[mf][nf] = __builtin_amdgcn_mfma_f32_16x16x32_bf16(       \
                    AH[mf], BH[nf], acc[mf][nf], 0, 0, 0);                   \
        _Pragma("unroll")                                                    \
        for (int mf = 0; mf < 4; ++mf)                                       \
            _Pragma("unroll")                                                \
            for (int nf = 0; nf < 3; ++nf)                                   \
                acc[mf][nf] = __builtin_amdgcn_mfma_f32_16x16x32_bf16(       \
                    AH[mf], BL[nf], acc[mf][nf], 0, 0, 0);                   \
        _Pragma("unroll")                                                    \
        for (int mf = 0; mf < 4; ++mf)                                       \
            _Pragma("unroll")                                                \
            for (int nf = 0; nf < 3; ++nf)                                   \
                acc[mf][nf] = __builtin_amdgcn_mfma_f32_16x16x32_bf16(       \
                    AL[mf], BH[nf], acc[mf][nf], 0, 0, 0);                   \
    }

#define STOREACC(MB)                                                         \
    {                                                                        \
        const int b_  = (MB) >> 12;                                          \
        const int tb_ = ((MB) & 4095) + lkg * 4;                             \
        _Pragma("unroll")                                                    \
        for (int mf = 0; mf < 4; ++mf) {                                     \
            int t = tb_ + mf * 16;                                           \
            _Pragma("unroll")                                                \
            for (int nf = 0; nf < 3; ++nf) {                                 \
                int c = n0 + nf * 16 + l15;                                  \
                f32x4 v = acc[mf][nf];                                       \
                if (mat == 2) {                                              \
                    v.x = 1.0f / (1.0f + expf(-v.x));                        \
                    v.y = 1.0f / (1.0f + expf(-v.y));                        \
                    v.z = 1.0f / (1.0f + expf(-v.z));                        \
                    v.w = 1.0f / (1.0f + expf(-v.w));                        \
                }                                                            \
                *(f32x4*)&Out[((size_t)(b_ * DIM + c)) * NT + t] = v;        \
            }                                                                \
        }                                                                    \
    }

#define ZEROACC                                                              \
    {                                                                        \
        _Pragma("unroll")                                                    \
        for (int i = 0; i < 4; ++i)                                          \
            _Pragma("unroll")                                                \
            for (int j = 0; j < 3; ++j)                                      \
                acc[i][j] = (f32x4){0.f, 0.f, 0.f, 0.f};                     \
    }

#define FENCE __builtin_amdgcn_sched_barrier(0)

__global__ __launch_bounds__(256, 2) void k_gemm_qkv_ws(
        const unsigned short* __restrict__ xs_hi,
        const unsigned short* __restrict__ xs_lo,
        const unsigned short* __restrict__ Whi,
        const unsigned short* __restrict__ Wlo,
        float* __restrict__ kT, float* __restrict__ vT, float* __restrict__ srT) {
    __shared__ __align__(16) short Bs[2][NKG][BN][8];   // 36,864 B

    const int tid  = threadIdx.x;
    const int lane = tid & 63;
    const int wid  = tid >> 6;          // 0..3
    const int l15  = lane & 15;
    const int lkg  = lane >> 4;         // 0..3
    const int kofs = lkg * 8;

    // swizzle: 768 blocks = 8 xcd * (8 groups-of-4-mtiles * 12 (slice,mat))
    const int bid   = blockIdx.x;
    const int xcd   = bid & 7;
    const int g     = bid >> 3;         // 0..95
    const int sm    = g % 12;
    const int grp   = g / 12;           // 0..7
    const int slice = sm & 3;           // 0..3
    const int mat   = sm >> 2;          // 0..2
    const int n0    = slice * BN;

    const unsigned short* Wh = Whi + mat * (DIM * DIM);
    const unsigned short* Wl = Wlo + mat * (DIM * DIM);
    float* Out = (mat == 0) ? kT : (mat == 1 ? vT : srT);

    // ---- stage W slice (hi+lo) into LDS: 2304 granules, 9 rounds ----
    #pragma unroll
    for (int r = 0; r < 9; ++r) {
        int gg = r * 256 + tid;
        int g2 = (gg >= 1152) ? gg - 1152 : gg;
        const unsigned short* src = (gg >= 1152) ? Wl : Wh;
        int kg  = g2 / BN;
        int col = g2 - kg * BN;
        int doff = (r * 256 + wid * 64) * 16;   // wave-uniform base; HW adds lane*16
        gload16(src + (size_t)(n0 + col) * DIM + kg * 8, (char*)&Bs[0][0][0][0] + doff);
    }

    const int mt0  = xcd * 32 + grp * 4;     // first of this block's 4 m-tiles
    const int wrow = wid * 64 + l15;         // lane's row within an m-tile

    f32x4 acc[4][3];
    ZEROACC

    short8 ah0[4], al0[4], ah1[4], al1[4], ah2[4], al2[4];
    short8 bh0[3], bl0[3], bh1[3], bl1[3];

    // 3-deep A prefetch for m-tile 0; barrier drains with W staging
    {
        const int r0 = mt0 * 256 + wrow;
        LOADA(ah0, al0, r0, 0)
        LOADA(ah1, al1, r0, 1)
        LOADA(ah2, al2, r0, 2)
    }
    __syncthreads();                      // W staged

    LOADB(bh0, bl0, 0)
    LOADB(bh1, bl1, 1)

    for (int mt = 0; mt < 4; ++mt) {
        const int rowc = (mt0 + mt) * 256 + wrow;
        const int rown = (mt < 3) ? rowc + 256 : rowc;   // clamp: last iter loads unused
        FENCE;
        COMP(ah0, al0, bh0, bl0)              // kc0
        FENCE;
        LOADA(ah0, al0, rowc, 3)
        LOADB(bh0, bl0, 2)
        FENCE;
        COMP(ah1, al1, bh1, bl1)              // kc1
        FENCE;
        LOADA(ah1, al1, rowc, 4)
        LOADB(bh1, bl1, 3)
        FENCE;
        COMP(ah2, al2, bh0, bl0)              // kc2
        FENCE;
        LOADA(ah2, al2, rowc, 5)
        LOADB(bh0, bl0, 4)
        FENCE;
        COMP(ah0, al0, bh1, bl1)              // kc3
        FENCE;
        LOADA(ah0, al0, rown, 0)
        LOADB(bh1, bl1, 5)
        FENCE;
        COMP(ah1, al1, bh0, bl0)              // kc4
        FENCE;
        LOADA(ah1, al1, rown, 1)
        LOADB(bh0, bl0, 0)                    // wrap for next m-tile
        FENCE;
        COMP(ah2, al2, bh1, bl1)              // kc5
        FENCE;
        LOADA(ah2, al2, rown, 2)
        LOADB(bh1, bl1, 1)
        FENCE;
        const int mb = (mt0 + mt) * 256 + wid * 64;
        STOREACC(mb)
        ZEROACC
    }
}

// ---------------------------------------------------------------------------
// Kernel 4: bidirectional WKV4 (unchanged). One block per (b,c).
__global__ __launch_bounds__(256) void k_wkv(
        const float* __restrict__ kT, const float* __restrict__ vT,
        const float* __restrict__ srT, const float* __restrict__ decay,
        const float* __restrict__ boost, float* __restrict__ zT) {
    __shared__ float sa[256], sb[256];
    int bc = blockIdx.x;
    int c = bc % DIM;
    size_t base = (size_t)bc * NT;
    int tid = threadIdx.x;
    int t0 = tid * 16;

    float w  = decay[c] * (1.0f / 4096.0f);
    float u  = boost[c] * (1.0f / 4096.0f);
    float ew = expf(-w);
    float eu = expf(u);

    float ek[16], ekv[16], vv[16];
    #pragma unroll
    for (int j = 0; j < 16; j += 4) {
        float4 k4 = *(const float4*)&kT[base + t0 + j];
        float4 v4 = *(const float4*)&vT[base + t0 + j];
        ek[j + 0] = expf(k4.x); ek[j + 1] = expf(k4.y);
        ek[j + 2] = expf(k4.z); ek[j + 3] = expf(k4.w);
        vv[j + 0] = v4.x; vv[j + 1] = v4.y; vv[j + 2] = v4.z; vv[j + 3] = v4.w;
        ekv[j + 0] = ek[j + 0] * v4.x; ekv[j + 1] = ek[j + 1] * v4.y;
        ekv[j + 2] = ek[j + 2] * v4.z; ekv[j + 3] = ek[j + 3] * v4.w;
    }

    float r = ew * ew; r = r * r; r = r * r; r = r * r;   // ew^16

    float La = 0.f, Lb = 0.f;
    #pragma unroll
    for (int j = 0; j < 16; ++j) { La = fmaf(ew, La, ekv[j]); Lb = fmaf(ew, Lb, ek[j]); }
    sa[tid] = La; sb[tid] = Lb;
    __syncthreads();
    float f = r;
    for (int d = 1; d < 256; d <<= 1) {
        float ta = (tid >= d) ? sa[tid - d] : 0.f;
        float tb_ = (tid >= d) ? sb[tid - d] : 0.f;
        __syncthreads();
        sa[tid] = fmaf(f, ta, sa[tid]);
        sb[tid] = fmaf(f, tb_, sb[tid]);
        __syncthreads();
        f = f * f;
    }
    float Ca = (tid > 0) ? sa[tid - 1] : 0.f;
    float Cb = (tid > 0) ? sb[tid - 1] : 0.f;
    __syncthreads();

    float Ra = 0.f, Rb = 0.f;
    #pragma unroll
    for (int j = 15; j >= 0; --j) { Ra = fmaf(ew, Ra, ekv[j]); Rb = fmaf(ew, Rb, ek[j]); }
    sa[255 - tid] = Ra; sb[255 - tid] = Rb;
    __syncthreads();
    f = r;
    for (int d = 1; d < 256; d <<= 1) {
        float ta = (tid >= d) ? sa[tid - d] : 0.f;
        float tb_ = (tid >= d) ? sb[tid - d] : 0.f;
        __syncthreads();
        sa[tid] = fmaf(f, ta, sa[tid]);
        sb[tid] = fmaf(f, tb_, sb[tid]);
        __syncthreads();
        f = f * f;
    }
    float Da = (tid < 255) ? sa[254 - tid] : 0.f;
    float Db = (tid < 255) ? sb[254 - tid] : 0.f;

    float ab[16], bb[16];
    {
        float a = Da, bv = Db;
        #pragma unroll
        for (int j = 15; j >= 0; --j) {
            ab[j] = a; bb[j] = bv;
            a  = fmaf(ew, a, ekv[j]);
            bv = fmaf(ew, bv, ek[j]);
        }
    }
    float outv[16];
    {
        float a = Ca, bv = Cb;
        #pragma unroll
        for (int j = 0; j < 16; ++j) {
            float af = a, bf = bv;
            a  = fmaf(ew, a, ekv[j]);
            bv = fmaf(ew, bv, ek[j]);
            float euk = eu * ek[j];
            float num = af + ab[j] + euk * vv[j];
            float den = bf + bb[j] + euk;
            outv[j] = num / den;
        }
    }
    #pragma unroll
    for (int j = 0; j < 16; j += 4) {
        float4 s4 = *(const float4*)&srT[base + t0 + j];
        float4 o;
        o.x = s4.x * outv[j + 0];
        o.y = s4.y * outv[j + 1];
        o.z = s4.z * outv[j + 2];
        o.w = s4.w * outv[j + 3];
        *(float4*)&zT[base + t0 + j] = o;
    }
}

// ---------------------------------------------------------------------------
// Kernel 5: output projection via split-bf16 MFMA (unchanged from round 8).

#define OSTAGE(BF, KC)                                                       \
    {                                                                        \
        _Pragma("unroll")                                                    \
        for (int pass = 0; pass < 2; ++pass) {                               \
            int t = stq * 4 + pass * 64;                                     \
            const float* z0 = &zT[((size_t)(b * DIM + (KC) * 32 + cp * 2)) * NT + t0 + t]; \
            float4 v0 = *(const float4*)z0;                                  \
            float4 v1 = *(const float4*)(z0 + NT);                           \
            _Pragma("unroll")                                                \
            for (int j = 0; j < 4; ++j) {                                    \
                float f0 = ((const float*)&v0)[j];                           \
                float f1 = ((const float*)&v1)[j];                           \
                unsigned short h0 = f2bf(f0), h1 = f2bf(f1);                 \
                unsigned int hw = (unsigned int)h0 | ((unsigned int)h1 << 16); \
                unsigned int lw = (unsigned int)f2bf(f0 - bf2f(h0))          \
                                | ((unsigned int)f2bf(f1 - bf2f(h1)) << 16); \
                *(unsigned int*)&Ah[BF][t + j][cp * 2] = hw;                 \
                *(unsigned int*)&Al[BF][t + j][cp * 2] = lw;                 \
            }                                                                \
        }                                                                    \
    }

#define OCOMP(BF, KC)                                                        \
    {                                                                        \
        short8 afh[4], afl[4], bfh[3], bfl[3];                               \
        _Pragma("unroll")                                                    \
        for (int mf = 0; mf < 4; ++mf) {                                     \
            int row = wm * 64 + mf * 16 + l15;                               \
            afh[mf] = *(const short8*)&Ah[BF][row][lkg * 8];                 \
            afl[mf] = *(const short8*)&Al[BF][row][lkg * 8];                 \
        }                                                                    \
        _Pragma("unroll")                                                    \
        for (int nf = 0; nf < 3; ++nf) {                                     \
            size_t wb = (size_t)(n0 + wn * 48 + nf * 16 + l15) * DIM + (KC) * 32 + lkg * 8; \
            bfh[nf] = *(const short8*)&Wohi[wb];                             \
            bfl[nf] = *(const short8*)&Wolo[wb];                             \
        }                                                                    \
        _Pragma("unroll")                                                    \
        for (int mf = 0; mf < 4; ++mf)                                       \
            _Pragma("unroll")                                                \
            for (int nf = 0; nf < 3; ++nf)                                   \
                acc[mf][nf] = __builtin_amdgcn_mfma_f32_16x16x32_bf16(       \
                    afh[mf], bfh[nf], acc[mf][nf], 0, 0, 0);                 \
        _Pragma("unroll")                                                    \
        for (int mf = 0; mf < 4; ++mf)                                       \
            _Pragma("unroll")                                                \
            for (int nf = 0; nf < 3; ++nf)                                   \
                acc[mf][nf] = __builtin_amdgcn_mfma_f32_16x16x32_bf16(       \
                    afh[mf], bfl[nf], acc[mf][nf], 0, 0, 0);                 \
        _Pragma("unroll")                                                    \
        for (int mf = 0; mf < 4; ++mf)                                       \
            _Pragma("unroll")                                                \
            for (int nf = 0; nf < 3; ++nf)                                   \
                acc[mf][nf] = __builtin_amdgcn_mfma_f32_16x16x32_bf16(       \
                    afl[mf], bfh[nf], acc[mf][nf], 0, 0, 0);                 \
    }

__global__ __launch_bounds__(256) void k_gemm_out_mfma(
        const float* __restrict__ zT,
        const unsigned short* __restrict__ Wohi,
        const unsigned short* __restrict__ Wolo,
        float* __restrict__ out) {
    __shared__ __align__(16) unsigned short Ah[2][128][40];   // 80B rows
    __shared__ __align__(16) unsigned short Al[2][128][40];   // total 40,960B

    const int tid  = threadIdx.x;
    const int lane = tid & 63;
    const int wid  = tid >> 6;
    const int wm = wid >> 1, wn = wid & 1;
    const int l15 = lane & 15;
    const int lkg = lane >> 4;
    const int n0 = blockIdx.x * 96;
    const int m0 = (int)blockIdx.y * 128;
    const int b  = m0 >> 12;
    const int t0 = m0 & 4095;

    const int cp  = tid >> 4;       // 0..15 (c-pair within 32-c chunk)
    const int stq = tid & 15;       // 0..15 (t quad)

    f32x4 acc[4][3];
    #pragma unroll
    for (int i = 0; i < 4; ++i)
        #pragma unroll
        for (int j = 0; j < 3; ++j)
            acc[i][j] = (f32x4){0.f, 0.f, 0.f, 0.f};

    OSTAGE(0, 0)
    __syncthreads();
    #pragma unroll
    for (int kc = 0; kc < 6; ++kc) {
        if (kc < 5) OSTAGE((kc + 1) & 1, kc + 1)
        OCOMP(kc & 1, kc)
        __syncthreads();
    }

    #pragma unroll
    for (int mf = 0; mf < 4; ++mf) {
        int trow = m0 + wm * 64 + mf * 16 + lkg * 4;
        #pragma unroll
        for (int nf = 0; nf < 3; ++nf) {
            int ncol = n0 + wn * 48 + nf * 16 + l15;
            #pragma unroll
            for (int j = 0; j < 4; ++j)
                out[(size_t)(trow + j) * DIM + ncol] = acc[mf][nf][j];
        }
    }
}

// ---------------------------------------------------------------------------
extern "C" void kernel_launch(void* const* d_in, const int* in_sizes, int n_in,
                              void* d_out, int out_size, void* d_ws, size_t ws_size,
                              hipStream_t stream) {
    const float* x     = (const float*)d_in[0];
    const float* w1    = (const float*)d_in[1];
    const float* w3    = (const float*)d_in[2];
    const float* w5    = (const float*)d_in[3];
    const float* alpha = (const float*)d_in[4];
    const float* Wk    = (const float*)d_in[5];
    const float* Wv    = (const float*)d_in[6];
    const float* Wr    = (const float*)d_in[7];
    const float* Wo    = (const float*)d_in[8];
    const float* decay = (const float*)d_in[9];
    const float* boost = (const float*)d_in[10];
    float* out = (float*)d_out;
    float* ws  = (float*)d_ws;

    const size_t BIG = (size_t)NB * NT * DIM;   // 12,582,912 elements

    // layout (float offsets):
    float* wc = ws;                                          // [0, 4800)
    unsigned short* Whi = (unsigned short*)(ws + 8192);      // 4*36864 ushorts -> ends 81920
    unsigned short* Wlo = (unsigned short*)(ws + 81920);     // -> ends 155648
    unsigned short* xs_hi = (unsigned short*)(ws + 155648);  // BIG ushorts -> ends 6447104
    unsigned short* xs_lo = xs_hi + BIG;                     // -> ends 12738560
    float* kT  = ws + 12738560;                              // BIG floats
    float* vT  = kT + BIG;
    float* srT = vT + BIG;                                   // ends 50487296 floats
    float* zT  = ws + 155648;   // fp32, overlays xs_hi/xs_lo (dead after qkv)

    hipLaunchKernelGGL(k_prep, dim3(577), dim3(256), 0, stream,
                       w1, w3, w5, alpha, Wk, Wv, Wr, Wo, wc, Whi, Wlo);
    hipLaunchKernelGGL(k_conv, dim3(NB * NH), dim3(DIM), 0, stream,
                       x, wc, xs_hi, xs_lo);
    // 768 blocks = 8 xcd * 8 groups-of-4-mtiles * 12 (slice,mat); swizzle in-kernel.
    hipLaunchKernelGGL(k_gemm_qkv_ws, dim3(768), dim3(256), 0, stream,
                       xs_hi, xs_lo, Whi, Wlo, kT, vT, srT);
    hipLaunchKernelGGL(k_wkv, dim3(NB * DIM), dim3(256), 0, stream,
                       kT, vT, srT, decay, boost, zT);
    hipLaunchKernelGGL(k_gemm_out_mfma, dim3(2, 65536 / 128), dim3(256), 0, stream,
                       zT, Whi + 3 * DIM * DIM, Wlo + 3 * DIM * DIM, out);
}